// Round 10
// baseline (256.296 us; speedup 1.0000x reference)
//
#include <hip/hip_runtime.h>
#include <hip/hip_bf16.h>

typedef __attribute__((ext_vector_type(4))) float f32x4;
typedef __attribute__((ext_vector_type(16))) float f32x16;
typedef __attribute__((ext_vector_type(8))) short bf16x8;

#define MFMA16(a, b, c) __builtin_amdgcn_mfma_f32_16x16x32_bf16(a, b, c, 0, 0, 0)
#define MFMA32(a, b, c) __builtin_amdgcn_mfma_f32_32x32x16_bf16(a, b, c, 0, 0, 0)

#define AS1(p) ((const __attribute__((address_space(1))) void*)(p))
#define AS3(p) ((__attribute__((address_space(3))) void*)(p))

// XOR swizzle of 16B slot within a 128B row (8 slots)
#define SWZK(r) ((((r) & 7)) ^ ((((r) >> 3) & 1) << 2))

__device__ __forceinline__ unsigned short f2bf(float f) {
  union { float f; unsigned u; } x; x.f = f;
  unsigned r = x.u + 0x7fffu + ((x.u >> 16) & 1u);  // RNE
  return (unsigned short)(r >> 16);
}
__device__ __forceinline__ float bfl(unsigned u) {
  union { unsigned u; float f; } x; x.u = u << 16; return x.f;
}
__device__ __forceinline__ float bfh(unsigned u) {
  union { unsigned u; float f; } x; x.u = u & 0xffff0000u; return x.f;
}

// ------------- merged input conversion: f32->bf16 (+Wq pre-scale), mask->u8
__global__ __launch_bounds__(256) void convert_inputs(
    const float* __restrict__ x, const float* __restrict__ wq,
    const float* __restrict__ wk, const float* __restrict__ wv,
    const float* __restrict__ wo, const int* __restrict__ mask,
    unsigned short* __restrict__ dst, unsigned char* __restrict__ mdst) {
  const int NX = 4194304, NW = 1048576;
  if (blockIdx.x < 4096) {
    const int i = blockIdx.x * 256 + threadIdx.x;
    const long base = (long)i * 8;
    const float* src; long off; float sc = 1.0f;
    if (base < NX) { src = x; off = base; }
    else {
      long j = base - NX; int wsI = (int)(j >> 20); off = j & (NW - 1);
      src = (wsI == 0) ? wq : (wsI == 1) ? wk : (wsI == 2) ? wv : wo;
      if (wsI == 0) sc = 0.18033688f;  // 0.125 * log2(e): QK lands in exp2 domain
    }
    float4 a = *(const float4*)(src + off);
    float4 b = *(const float4*)(src + off + 4);
    uint4 o;
    o.x = (unsigned)f2bf(a.x * sc) | ((unsigned)f2bf(a.y * sc) << 16);
    o.y = (unsigned)f2bf(a.z * sc) | ((unsigned)f2bf(a.w * sc) << 16);
    o.z = (unsigned)f2bf(b.x * sc) | ((unsigned)f2bf(b.y * sc) << 16);
    o.w = (unsigned)f2bf(b.z * sc) | ((unsigned)f2bf(b.w * sc) << 16);
    ((uint4*)dst)[i] = o;
  } else {
    const int i = (blockIdx.x - 4096) * 256 + threadIdx.x;  // x4 elements
    const int4 v = ((const int4*)mask)[i];
    uchar4 r;
    r.x = (unsigned char)v.x; r.y = (unsigned char)v.y;
    r.z = (unsigned char)v.z; r.w = (unsigned char)v.w;
    ((uchar4*)mdst)[i] = r;
  }
}

// ---------------- templated BMxBN NT GEMM mainloop (C = A * W^T), K=1024 ---
template <int BM, int BN>
__device__ __forceinline__ void gemm_nt(
    const unsigned short* __restrict__ A, const unsigned short* __restrict__ Bw,
    int m0, int n0, unsigned short* Al, unsigned short* Bl, f32x4* acc) {
  const int t = threadIdx.x;
  const int l = t & 63;
  const int w = t >> 6, wr = w >> 1, wc = w & 1;
  const int lc = l & 15, lg = l >> 4;
  constexpr int MI = BM / 32, NJ = BN / 32;
  constexpr int ASZ = BM * 32, BSZ = BN * 32;

  auto stage = [&](int buf, int kt) {
    const int k0 = kt * 32;
#pragma unroll
    for (int c = 0; c < BM / 64; ++c) {
      const int e = (t + c * 256) * 8;
      __builtin_amdgcn_global_load_lds(
          AS1(A + (size_t)(m0 + (e >> 5)) * 1024 + k0 + (e & 31)),
          AS3(Al + buf * ASZ + e), 16, 0, 0);
    }
#pragma unroll
    for (int c = 0; c < BN / 64; ++c) {
      const int e = (t + c * 256) * 8;
      __builtin_amdgcn_global_load_lds(
          AS1(Bw + (size_t)(n0 + (e >> 5)) * 1024 + k0 + (e & 31)),
          AS3(Bl + buf * BSZ + e), 16, 0, 0);
    }
  };

  stage(0, 0);
#pragma unroll 2
  for (int kt = 0; kt < 32; ++kt) {
    __syncthreads();
    if (kt + 1 < 32) stage((kt + 1) & 1, kt + 1);
    const unsigned short* Ab = Al + (kt & 1) * ASZ;
    const unsigned short* Bb = Bl + (kt & 1) * BSZ;
    bf16x8 af[MI], bfr[NJ];
#pragma unroll
    for (int i = 0; i < MI; ++i)
      af[i] = *(const bf16x8*)(Ab + (wr * (BM / 2) + i * 16 + lc) * 32 + lg * 8);
#pragma unroll
    for (int j = 0; j < NJ; ++j)
      bfr[j] = *(const bf16x8*)(Bb + (wc * (BN / 2) + j * 16 + lc) * 32 + lg * 8);
#pragma unroll
    for (int i = 0; i < MI; ++i)
#pragma unroll
      for (int j = 0; j < NJ; ++j)
        acc[i * NJ + j] = MFMA16(af[i], bfr[j], acc[i * NJ + j]);
  }
}

// ---------------- QKV projection: Q,K -> (B,H,S,64); V -> (B,H,64,S) -------
// 128x64 tiles: grid (32,16,3) = 1536 blocks.
__global__ __launch_bounds__(256, 5) void gemm_qkv(
    const unsigned short* __restrict__ xb,
    const unsigned short* __restrict__ wqb, const unsigned short* __restrict__ wkb,
    const unsigned short* __restrict__ wvb,
    unsigned short* __restrict__ q, unsigned short* __restrict__ k,
    unsigned short* __restrict__ vt) {
  __shared__ unsigned short Al[2 * 4096], Bl[2 * 2048];
  const int z = blockIdx.z;
  const unsigned short* Bw = (z == 0) ? wqb : (z == 1) ? wkb : wvb;
  const int m0 = blockIdx.x * 128, n0 = blockIdx.y * 64;
  f32x4 acc[8] = {};
  gemm_nt<128, 64>(xb, Bw, m0, n0, Al, Bl, acc);

  const int l = threadIdx.x & 63, w = threadIdx.x >> 6;
  const int wr = w >> 1, wc = w & 1, lc = l & 15, lg = l >> 4;

  if (z == 2) {
#pragma unroll
    for (int i = 0; i < 4; ++i)
#pragma unroll
      for (int j = 0; j < 2; ++j) {
        const int m = m0 + wr * 64 + i * 16 + lg * 4;
        const int n = n0 + wc * 32 + j * 16 + lc;
        const int b = m >> 11, s = m & 2047, hh = n >> 6, hd = n & 63;
        ushort4 pk;
        pk.x = f2bf(acc[i * 2 + j][0]); pk.y = f2bf(acc[i * 2 + j][1]);
        pk.z = f2bf(acc[i * 2 + j][2]); pk.w = f2bf(acc[i * 2 + j][3]);
        *(ushort4*)(vt + (size_t)((b << 4) + hh) * 131072 + (size_t)hd * 2048 + s) = pk;
      }
  } else {
    unsigned short* C = (z == 0) ? q : k;
#pragma unroll
    for (int i = 0; i < 4; ++i)
#pragma unroll
      for (int j = 0; j < 2; ++j)
#pragma unroll
        for (int r = 0; r < 4; ++r) {
          const int m = m0 + wr * 64 + i * 16 + lg * 4 + r;
          const int n = n0 + wc * 32 + j * 16 + lc;
          const int b = m >> 11, s = m & 2047, hh = n >> 6, hd = n & 63;
          C[(size_t)((b << 4) + hh) * 131072 + s * 64 + hd] = f2bf(acc[i * 2 + j][r]);
        }
  }
}

// ---------------- output projection: out = ao @ Wo^T + bo, 64x64 tiles -----
__global__ __launch_bounds__(256, 4) void gemm_out(
    const unsigned short* __restrict__ ao, const unsigned short* __restrict__ wob,
    const float* __restrict__ bias, float* __restrict__ out) {
  __shared__ unsigned short Al[2 * 2048], Bl[2 * 2048];
  const int m0 = blockIdx.x * 64, n0 = blockIdx.y * 64;
  f32x4 acc[4] = {};
  gemm_nt<64, 64>(ao, wob, m0, n0, Al, Bl, acc);

  const int l = threadIdx.x & 63, w = threadIdx.x >> 6;
  const int wr = w >> 1, wc = w & 1, lc = l & 15, lg = l >> 4;
#pragma unroll
  for (int i = 0; i < 2; ++i)
#pragma unroll
    for (int j = 0; j < 2; ++j)
#pragma unroll
      for (int r = 0; r < 4; ++r) {
        const int m = m0 + wr * 32 + i * 16 + lg * 4 + r;
        const int n = n0 + wc * 32 + j * 16 + lc;
        out[(size_t)m * 1024 + n] = acc[i * 2 + j][r] + bias[n];
      }
}

// ---------------- flash attention, kv-split x2, bf16 unnormalized partials -
// blockIdx.y = kv half. half0 -> p0 (=aob region), half1 -> p1 (=xb region).
// Mask read as 8 register dwords/tile (one 64B line per q-row, no LDS).
// LDS 32KB -> 4 blocks/CU; grid (512,2) = 1024 blocks = 4/CU.
__global__ __launch_bounds__(256, 4) void attn_fwd(
    const unsigned short* __restrict__ q, const unsigned short* __restrict__ k,
    const unsigned short* __restrict__ vt, const unsigned char* __restrict__ mb8,
    unsigned short* __restrict__ p0, unsigned short* __restrict__ p1,
    float* __restrict__ lpart) {
  __shared__ unsigned short Kl[2][4096];  // [64 kv][64 d] swizzled, 8KB x2
  __shared__ unsigned short Vl[2][4096];  // [64 d][64 kv] swizzled, 8KB x2
  const int orig = blockIdx.x;            // 512 blocks, 8 XCDs, 64/XCD
  const int nid = (orig & 7) * 64 + (orig >> 3);
  const int half = blockIdx.y;
  const int bh = nid >> 4, b = bh >> 4, h = bh & 15;
  const int q0 = (nid & 15) * 128;
  const int t = threadIdx.x, l = t & 63, w = t >> 6;
  const int lq = l & 31, hh = l >> 5;
  const int qq = w * 32 + lq;  // q row within block tile

  // Q B-frags (col=q=lane&31, k=d=s*16+hh*8+j), held all kernel
  const unsigned short* qp = q + ((size_t)bh * 2048 + q0 + qq) * 64;
  bf16x8 qa[4];
#pragma unroll
  for (int s = 0; s < 4; ++s) qa[s] = *(const bf16x8*)(qp + s * 16 + hh * 8);

  const unsigned short* kp = k + (size_t)bh * 131072;
  const unsigned short* vp = vt + (size_t)bh * 131072;
  // per-thread mask row base: all 8 dwords of a tile live in ONE 64B line
  const unsigned char* mrow = mb8 + (size_t)b * 4194304 + (size_t)(q0 + qq) * 2048;

  f32x16 oa[2] = {};
  float lsum = 0.f;

  auto stage = [&](int buf, int kv0) {
#pragma unroll
    for (int c = 0; c < 2; ++c) {
      const int idx = c * 256 + w * 64 + l;  // 16B-chunk 0..511
      const int row = idx >> 3, ch = idx & 7;
      __builtin_amdgcn_global_load_lds(
          AS1(kp + (size_t)(kv0 + row) * 64 + (ch ^ SWZK(row)) * 8),
          AS3(&Kl[buf][(c * 256 + w * 64) * 8]), 16, 0, 0);
      __builtin_amdgcn_global_load_lds(
          AS1(vp + (size_t)row * 2048 + kv0 + (ch ^ SWZK(row)) * 8),
          AS3(&Vl[buf][(c * 256 + w * 64) * 8]), 16, 0, 0);
    }
  };

  const int kvbase = half * 1024;  // 16 tiles of 64
  stage(0, kvbase);
  for (int tt = 0; tt < 16; ++tt) {
    const int kv0 = kvbase + tt * 64;
    __syncthreads();  // stage(tt) landed; prev-tile reads done

    // mask dwords for THIS tile, issued before next-tile staging so their
    // waitcnt doesn't drain the staging loads
    unsigned mreg[8];
#pragma unroll
    for (int cb = 0; cb < 2; ++cb)
#pragma unroll
      for (int g = 0; g < 4; ++g)
        mreg[cb * 4 + g] = *(const unsigned*)(mrow + kv0 + cb * 32 + g * 8 + hh * 4);

    if (tt + 1 < 16) stage((tt + 1) & 1, kv0 + 64);
    const unsigned short* Kb = Kl[tt & 1];
    const unsigned short* Vb = Vl[tt & 1];

    // S^T += K . Q^T  (QK pre-scaled to exp2 domain)
    f32x16 sa[2] = {};
    __builtin_amdgcn_s_setprio(1);
#pragma unroll
    for (int s = 0; s < 4; ++s) {
#pragma unroll
      for (int cb = 0; cb < 2; ++cb) {
        const int row = cb * 32 + lq;
        bf16x8 kf = *(const bf16x8*)(Kb + row * 64 + (((2 * s + hh) ^ SWZK(row))) * 8);
        sa[cb] = MFMA32(kf, qa[s], sa[cb]);
      }
    }
    __builtin_amdgcn_s_setprio(0);

    // mask + exp2 in place; accumulate row sum
#pragma unroll
    for (int cb = 0; cb < 2; ++cb)
#pragma unroll
      for (int g = 0; g < 4; ++g) {
        const unsigned mdw = mreg[cb * 4 + g];
#pragma unroll
        for (int i = 0; i < 4; ++i) {
          const float mf = (float)((mdw >> (8 * i)) & 255u);
          const float e = __builtin_amdgcn_exp2f(fmaf(mf, -100.f, sa[cb][4 * g + i]));
          sa[cb][4 * g + i] = e;
          lsum += e;
        }
      }

    // P -> A-frags in-register (cvt_pk + permlane32_swap), then O += P @ V
    __builtin_amdgcn_s_setprio(1);
#pragma unroll
    for (int s = 0; s < 4; ++s) {
      const int cb = s >> 1, gb = 2 * (s & 1);
      unsigned pk00, pk01, pk10, pk11;
      asm("v_cvt_pk_bf16_f32 %0, %1, %2" : "=v"(pk00) : "v"(sa[cb][4 * gb + 0]), "v"(sa[cb][4 * gb + 1]));
      asm("v_cvt_pk_bf16_f32 %0, %1, %2" : "=v"(pk01) : "v"(sa[cb][4 * gb + 2]), "v"(sa[cb][4 * gb + 3]));
      asm("v_cvt_pk_bf16_f32 %0, %1, %2" : "=v"(pk10) : "v"(sa[cb][4 * gb + 4]), "v"(sa[cb][4 * gb + 5]));
      asm("v_cvt_pk_bf16_f32 %0, %1, %2" : "=v"(pk11) : "v"(sa[cb][4 * gb + 6]), "v"(sa[cb][4 * gb + 7]));
      asm("v_permlane32_swap_b32 %0, %1" : "+v"(pk00), "+v"(pk10));
      asm("v_permlane32_swap_b32 %0, %1" : "+v"(pk01), "+v"(pk11));
      union { int4 i; bf16x8 v; } fr;
      fr.i = make_int4(pk00, pk01, pk10, pk11);
#pragma unroll
      for (int db = 0; db < 2; ++db) {
        const int row = db * 32 + lq;
        bf16x8 vf = *(const bf16x8*)(Vb + row * 64 + (((2 * s + hh) ^ SWZK(row))) * 8);
        oa[db] = MFMA32(fr.v, vf, oa[db]);
      }
    }
    __builtin_amdgcn_s_setprio(0);
  }

  // write bf16 unnormalized partial + f32 row-sum partial
  unsigned short* op = half ? p1 : p0;
#pragma unroll
  for (int r = 0; r < 16; ++r) {
    const int row = (r & 3) + 8 * (r >> 2) + 4 * hh;
    unsigned short* dst = op + ((size_t)b * 2048 + q0 + w * 32 + row) * 1024 + h * 64;
    dst[lq] = f2bf(oa[0][r]);
    dst[32 + lq] = f2bf(oa[1][r]);
  }
  lsum += __shfl_xor(lsum, 32, 64);
  if (hh == 0) lpart[half * 65536 + bh * 2048 + q0 + qq] = lsum;
}

// ---------------- combine kv-split bf16 partials -> bf16 ao (in place) -----
__global__ __launch_bounds__(256) void combine_o(
    const unsigned short* __restrict__ p1, const float* __restrict__ lp,
    unsigned short* __restrict__ ao) {
  const int i = blockIdx.x * 256 + threadIdx.x;  // x8 elements
  const long base = (long)i * 8;
  const int bi = (int)(base >> 21), s = (int)((base >> 10) & 2047),
            h = (int)((base >> 6) & 15);
  const int lidx = ((bi << 4) + h) * 2048 + s;
  const float inv = __builtin_amdgcn_rcpf(lp[lidx] + lp[65536 + lidx]);
  uint4 a = ((const uint4*)ao)[i];
  uint4 bq = ((const uint4*)p1)[i];
  uint4 o;
  o.x = (unsigned)f2bf((bfl(a.x) + bfl(bq.x)) * inv) | ((unsigned)f2bf((bfh(a.x) + bfh(bq.x)) * inv) << 16);
  o.y = (unsigned)f2bf((bfl(a.y) + bfl(bq.y)) * inv) | ((unsigned)f2bf((bfh(a.y) + bfh(bq.y)) * inv) << 16);
  o.z = (unsigned)f2bf((bfl(a.z) + bfl(bq.z)) * inv) | ((unsigned)f2bf((bfh(a.z) + bfh(bq.z)) * inv) << 16);
  o.w = (unsigned)f2bf((bfl(a.w) + bfl(bq.w)) * inv) | ((unsigned)f2bf((bfh(a.w) + bfh(bq.w)) * inv) << 16);
  ((uint4*)ao)[i] = o;
}

extern "C" void kernel_launch(void* const* d_in, const int* in_sizes, int n_in,
                              void* d_out, int out_size, void* d_ws, size_t ws_size,
                              hipStream_t stream) {
  const float* x = (const float*)d_in[0];
  const int* mask = (const int*)d_in[1];
  const float* Wq = (const float*)d_in[2];
  const float* Wk = (const float*)d_in[3];
  const float* Wv = (const float*)d_in[4];
  const float* Wo = (const float*)d_in[5];
  const float* bo = (const float*)d_in[6];

  // 56 MB layout (same envelope as rounds 1-6; xb/wqb reused after gemm_qkv)
  unsigned short* ws = (unsigned short*)d_ws;
  unsigned short* xb = ws;                   // (B*S,D) bf16; -> attn half1 partial
  unsigned short* wqb = xb + 4194304;        // pre-scaled Wq; -> lpart (f32 2x65536)
  unsigned short* wkb = wqb + 1048576;
  unsigned short* wvb = wkb + 1048576;
  unsigned short* wob = wvb + 1048576;
  unsigned short* qb = wob + 1048576;        // (B,H,S,64) bf16
  unsigned short* kb = qb + 4194304;         // (B,H,S,64) bf16
  unsigned short* vtb = kb + 4194304;        // (B,H,64,S) bf16
  unsigned short* aob = vtb + 4194304;       // attn half0 partial -> combined bf16
  unsigned char* mb8 = (unsigned char*)(aob + 4194304);  // 8.4MB u8 mask
  float* lpart = (float*)wqb;

  convert_inputs<<<dim3(12288), dim3(256), 0, stream>>>(x, Wq, Wk, Wv, Wo, mask, ws, mb8);
  gemm_qkv<<<dim3(32, 16, 3), dim3(256), 0, stream>>>(xb, wqb, wkb, wvb, qb, kb, vtb);
  attn_fwd<<<dim3(512, 2), dim3(256), 0, stream>>>(qb, kb, vtb, mb8, aob, xb, lpart);
  combine_o<<<dim3(2048), dim3(256), 0, stream>>>(xb, lpart, aob);
  gemm_out<<<dim3(64, 16), dim3(256), 0, stream>>>(aob, wob, bo, (float*)d_out);
}